// Round 5
// baseline (71.102 us; speedup 1.0000x reference)
//
#include <hip/hip_runtime.h>
#include <hip/hip_fp16.h>

typedef _Float16 half8 __attribute__((ext_vector_type(8)));
typedef _Float16 half2v __attribute__((ext_vector_type(2)));
typedef float f32x4 __attribute__((ext_vector_type(4)));

#define BM 64
#define BN 256
#define BK 64
#define SPLITK 8
#define LDS_HALF (BM * BK * 2 + BK * BN * 2)   // 40960 bytes per buffer

__device__ inline unsigned pkrtz(float lo, float hi) {
  return __builtin_bit_cast(unsigned, __builtin_amdgcn_cvt_pkrtz(lo, hi));
}

// raw barrier: no vmcnt drain (prefetch lives in registers; ds ordering via lgkmcnt)
#define BAR() do { \
  asm volatile("s_waitcnt lgkmcnt(0)" ::: "memory"); \
  __builtin_amdgcn_s_barrier(); \
  __builtin_amdgcn_sched_barrier(0); \
} while (0)

__global__ void init_out_kernel(const float* __restrict__ bias,
                                float* __restrict__ out, int MN, int N) {
  int i = (blockIdx.x * blockDim.x + threadIdx.x) * 4;
  if (i < MN) {
    *(float4*)(out + i) = *(const float4*)(bias + (i % N));
  }
}

struct Pf {
  float4 a0, a1;            // 8 fp32 of x
  int w0, w1, w2, w3;       // 4 packed qweight words (4 consecutive k-rows)
  unsigned zrep;            // fp16(1025+z) x2
  unsigned srep;            // fp16(s) x2
};

__global__ __launch_bounds__(512, 4) void qgemm_kernel(
    const float* __restrict__ x, const int* __restrict__ qw,
    const int* __restrict__ qz, const float* __restrict__ sc,
    float* __restrict__ out, int M, int N, int K) {
  __shared__ __align__(16) unsigned char smem[2 * LDS_HALF];  // 80 KB
  const int tid = threadIdx.x;
  const int n0 = blockIdx.x * BN;
  const int m0 = blockIdx.y * BM;
  const int KC = K / SPLITK;           // 512
  const int kbase = blockIdx.z * KC;
  const int nt = KC / BK;              // 8
  const int wid = tid >> 6;
  const int lane = tid & 63;
  const int wr = wid >> 2;   // 0..1  (M)
  const int wc = wid & 3;    // 0..3  (N)
  const int lcol = lane & 15;
  const int lk = lane >> 4;
  const int N8 = N >> 3;

  f32x4 acc[2][4] = {};

  // A staging: thread -> (row 0..63, k-group 0..7), 8 fp32
  const int arow = tid >> 3;
  const int acg = tid & 7;
  // B staging: thread -> (col 0..255, 4 packed rows brow4..brow4+3)
  const int bcol = tid & 255;
  const int brow4 = (tid >> 8) * 4;    // 0 or 4
  const int gn = n0 + bcol;

  auto LOAD = [&](int t, Pf& p) {
    int k0 = kbase + t * BK;
    const float* src = x + (m0 + arow) * K + k0 + acg * 8;
    p.a0 = *(const float4*)(src);
    p.a1 = *(const float4*)(src + 4);
    int g = k0 >> 7;
    int kq0 = (k0 >> 3) + brow4;
    p.w0 = qw[(kq0 + 0) * N + gn];
    p.w1 = qw[(kq0 + 1) * N + gn];
    p.w2 = qw[(kq0 + 2) * N + gn];
    p.w3 = qw[(kq0 + 3) * N + gn];
    int zv = (qz[g * N8 + (gn >> 3)] >> ((bcol & 7) * 4)) & 0xF;
    p.zrep = (0x6400u + (unsigned)zv + 1u) * 0x00010001u;
    float s = sc[g * N + gn];
    p.srep = pkrtz(s, s);
  };

  // k-order inside each 16B unit (A and B identical): [0,4,1,5,2,6,3,7]
  auto STORE = [&](int buf, const Pf& p) {
    unsigned char* base = smem + buf * LDS_HALF;
    uint4 aw;
    aw.x = pkrtz(p.a0.x, p.a1.x);
    aw.y = pkrtz(p.a0.y, p.a1.y);
    aw.z = pkrtz(p.a0.z, p.a1.z);
    aw.w = pkrtz(p.a0.w, p.a1.w);
    *(uint4*)(base + arow * 128 + ((acg ^ (arow & 7)) << 4)) = aw;

    unsigned char* bb = base + 8192;
    half2v zh = __builtin_bit_cast(half2v, p.zrep);
    half2v sh = __builtin_bit_cast(half2v, p.srep);
    const unsigned vw[4] = {(unsigned)p.w0, (unsigned)p.w1,
                            (unsigned)p.w2, (unsigned)p.w3};
#pragma unroll
    for (int j = 0; j < 4; ++j) {
      uint4 q;
#pragma unroll
      for (int b = 0; b < 4; ++b) {
        unsigned tt = ((vw[j] >> (4 * b)) & 0x000F000Fu) | 0x64006400u;
        half2v h = (__builtin_bit_cast(half2v, tt) - zh) * sh;
        (&q.x)[b] = __builtin_bit_cast(unsigned, h);
      }
      int unit = brow4 + j;
      *(uint4*)(bb + bcol * 128 + ((unit ^ (bcol & 7)) << 4)) = q;
    }
  };

  auto COMPUTE = [&](int buf) {
    unsigned char* base = smem + buf * LDS_HALF;
    unsigned char* bb = base + 8192;
#pragma unroll
    for (int kk = 0; kk < 2; ++kk) {
      half8 a[2], b[4];
      int unit = kk * 4 + lk;
#pragma unroll
      for (int fi = 0; fi < 2; ++fi) {
        int row = wr * 32 + fi * 16 + lcol;
        a[fi] = *(half8*)(base + row * 128 + ((unit ^ (row & 7)) << 4));
      }
#pragma unroll
      for (int fj = 0; fj < 4; ++fj) {
        int col = wc * 64 + fj * 16 + lcol;
        b[fj] = *(half8*)(bb + col * 128 + ((unit ^ (col & 7)) << 4));
      }
#pragma unroll
      for (int fi = 0; fi < 2; ++fi)
#pragma unroll
        for (int fj = 0; fj < 4; ++fj)
          acc[fi][fj] = __builtin_amdgcn_mfma_f32_16x16x32_f16(
              a[fi], b[fj], acc[fi][fj], 0, 0, 0);
    }
  };

  // prologue (full drain once)
  Pf sA, sB;
  LOAD(0, sA);
  STORE(0, sA);
  LOAD(1, sB);
  __syncthreads();

  // main loop: raw barriers, loads stay in flight across them
  for (int t = 0; t < nt; t += 2) {
    if (t + 2 < nt) LOAD(t + 2, sA);
    COMPUTE(0);
    STORE(1, sB);               // tile t+1, loaded one full phase ago
    BAR();

    if (t + 3 < nt) LOAD(t + 3, sB);
    COMPUTE(1);
    if (t + 2 < nt) STORE(0, sA);
    BAR();
  }

  // epilogue: atomic-accumulate split-K partials (bias pre-written by init)
#pragma unroll
  for (int fi = 0; fi < 2; ++fi) {
    int gm = m0 + wr * 32 + fi * 16 + lk * 4;
#pragma unroll
    for (int fj = 0; fj < 4; ++fj) {
      int gc = n0 + wc * 64 + fj * 16 + lcol;
#pragma unroll
      for (int r = 0; r < 4; ++r)
        unsafeAtomicAdd(&out[(gm + r) * N + gc], acc[fi][fj][r]);
    }
  }
}

extern "C" void kernel_launch(void* const* d_in, const int* in_sizes, int n_in,
                              void* d_out, int out_size, void* d_ws, size_t ws_size,
                              hipStream_t stream) {
  const float* x = (const float*)d_in[0];
  const int* qw = (const int*)d_in[1];
  const int* qz = (const int*)d_in[2];
  const float* sc = (const float*)d_in[3];
  const float* bias = (const float*)d_in[4];
  float* out = (float*)d_out;

  int N = in_sizes[4];
  int K = (in_sizes[1] / N) * 8;
  int M = in_sizes[0] / K;
  int MN = M * N;

  init_out_kernel<<<(MN / 4 + 255) / 256, 256, 0, stream>>>(bias, out, MN, N);

  dim3 grid(N / BN, M / BM, SPLITK);
  qgemm_kernel<<<grid, 512, 0, stream>>>(x, qw, qz, sc, out, M, N, K);
}

// Round 6
// 47.080 us; speedup vs baseline: 1.5103x; 1.5103x over previous
//
#include <hip/hip_runtime.h>
#include <hip/hip_fp16.h>

typedef _Float16 half8 __attribute__((ext_vector_type(8)));
typedef _Float16 half2v __attribute__((ext_vector_type(2)));
typedef float f32x16 __attribute__((ext_vector_type(16)));

#define BM 128
#define BN 256
#define BK 64
#define LDS_A (BM * BK * 2)        // 16 KB
#define LDS_B (BN * BK * 2)        // 32 KB
#define LDS_HALF (LDS_A + LDS_B)   // 48 KB

__device__ inline unsigned pkrtz(float lo, float hi) {
  return __builtin_bit_cast(unsigned, __builtin_amdgcn_cvt_pkrtz(lo, hi));
}

// raw barrier: lgkm drain only — global prefetch loads stay in flight
#define BAR() do { \
  asm volatile("s_waitcnt lgkmcnt(0)" ::: "memory"); \
  __builtin_amdgcn_s_barrier(); \
} while (0)

__global__ void init_out_kernel(const float* __restrict__ bias,
                                float* __restrict__ out, int MN, int N) {
  int i = (blockIdx.x * blockDim.x + threadIdx.x) * 4;
  if (i < MN) *(float4*)(out + i) = *(const float4*)(bias + (i % N));
}

__global__ void reduce_kernel(const float* __restrict__ ws,
                              const float* __restrict__ bias,
                              float* __restrict__ out, int MN, int N, int S) {
  int i = (blockIdx.x * blockDim.x + threadIdx.x) * 4;
  if (i >= MN) return;
  float4 a = *(const float4*)(bias + (i % N));
  for (int z = 0; z < S; ++z) {
    float4 p = *(const float4*)(ws + (size_t)z * MN + i);
    a.x += p.x; a.y += p.y; a.z += p.z; a.w += p.w;
  }
  *(float4*)(out + i) = a;
}

struct Pf {
  float4 a0, a1, a2, a3;    // 16 fp32 of x (one row, 16 k)
  int w0, w1, w2, w3;       // 4 packed qweight words (32 k)
  int zv;                   // raw zero nibble
  float s;                  // scale
};

__global__ __launch_bounds__(512, 2) void qgemm_kernel(
    const float* __restrict__ x, const int* __restrict__ qw,
    const int* __restrict__ qz, const float* __restrict__ sc,
    float* __restrict__ target, int N, int K, int S, int use_ws) {
  __shared__ __align__(16) unsigned char smem[2 * LDS_HALF];  // 96 KB
  const int tid = threadIdx.x;
  const int n0 = blockIdx.x * BN;
  const int z = blockIdx.z;
  const int KC = K / S;
  const int kbase = z * KC;
  const int nt = KC / BK;            // 8 at S=8
  const int lane = tid & 63;
  const int wid = tid >> 6;
  const int wr = wid >> 2;           // 0..1 (M, 64 rows each)
  const int wc = wid & 3;            // 0..3 (N, 64 cols each)
  const int l31 = lane & 31;
  const int l5 = lane >> 5;
  const int N8 = N >> 3;

  f32x16 acc[2][2] = {};

  // A staging: row = tid>>2 (128 rows), k-chunk = (tid&3)*16
  const int arow = tid >> 2;
  const int akc = tid & 3;           // unit pair index: units 2*akc, 2*akc+1
  // B staging: col = tid&255, half = tid>>8 -> 4 packed words (32 k)
  const int bcol = tid & 255;
  const int bh = tid >> 8;           // 0/1
  const int gn = n0 + bcol;

  auto LOAD = [&](int t, Pf& p) {
    int k0 = kbase + t * BK;
    const float* src = x + arow * K + k0 + akc * 16;
    p.a0 = *(const float4*)(src);
    p.a1 = *(const float4*)(src + 4);
    p.a2 = *(const float4*)(src + 8);
    p.a3 = *(const float4*)(src + 12);
    int g = k0 >> 7;
    int kq0 = (k0 >> 3) + bh * 4;
    p.w0 = qw[(kq0 + 0) * N + gn];
    p.w1 = qw[(kq0 + 1) * N + gn];
    p.w2 = qw[(kq0 + 2) * N + gn];
    p.w3 = qw[(kq0 + 3) * N + gn];
    p.zv = (qz[g * N8 + (gn >> 3)] >> ((bcol & 7) * 4)) & 0xF;
    p.s = sc[g * N + gn];
  };

  // k-order inside each 16B unit (A and B identical): [0,4,1,5,2,6,3,7]
  auto STORE = [&](int buf, const Pf& p) {
    unsigned char* base = smem + buf * LDS_HALF;
    // A: 16 fp32 -> 2 units, pairs (k, k+4)
    uint4 A0, A1;
    A0.x = pkrtz(p.a0.x, p.a1.x);  A0.y = pkrtz(p.a0.y, p.a1.y);
    A0.z = pkrtz(p.a0.z, p.a1.z);  A0.w = pkrtz(p.a0.w, p.a1.w);
    A1.x = pkrtz(p.a2.x, p.a3.x);  A1.y = pkrtz(p.a2.y, p.a3.y);
    A1.z = pkrtz(p.a2.z, p.a3.z);  A1.w = pkrtz(p.a3 /*k+12*/ .x * 0.f + p.a2.w, p.a3.w);
    // (fix: A1.w must pair a2.w with a3.w — see explicit line below)
    A1.w = pkrtz(p.a2.w, p.a3.w);
    int u0 = akc * 2;
    *(uint4*)(base + arow * 128 + (((u0 + 0) ^ (arow & 7)) << 4)) = A0;
    *(uint4*)(base + arow * 128 + (((u0 + 1) ^ (arow & 7)) << 4)) = A1;

    // B: dequant 4 words -> 4 units
    unsigned char* bb = base + LDS_A;
    unsigned zrep = (0x6400u + (unsigned)p.zv + 1u) * 0x00010001u;
    half2v zh = __builtin_bit_cast(half2v, zrep);
    unsigned srep = pkrtz(p.s, p.s);
    half2v sh = __builtin_bit_cast(half2v, srep);
    const unsigned vw[4] = {(unsigned)p.w0, (unsigned)p.w1,
                            (unsigned)p.w2, (unsigned)p.w3};
#pragma unroll
    for (int j = 0; j < 4; ++j) {
      uint4 q;
#pragma unroll
      for (int b = 0; b < 4; ++b) {
        unsigned tt = ((vw[j] >> (4 * b)) & 0x000F000Fu) | 0x64006400u;
        half2v h = (__builtin_bit_cast(half2v, tt) - zh) * sh;
        (&q.x)[b] = __builtin_bit_cast(unsigned, h);
      }
      int u = bh * 4 + j;
      *(uint4*)(bb + bcol * 128 + ((u ^ (bcol & 7)) << 4)) = q;
    }
  };

  auto COMPUTE = [&](int buf) {
    unsigned char* base = smem + buf * LDS_HALF;
    unsigned char* bb = base + LDS_A;
#pragma unroll
    for (int kk = 0; kk < 4; ++kk) {
      half8 a[2], b[2];
      int u = kk * 2 + l5;           // this lane-half's 8-k window
#pragma unroll
      for (int fi = 0; fi < 2; ++fi) {
        int row = wr * 64 + fi * 32 + l31;
        a[fi] = *(half8*)(base + row * 128 + ((u ^ (row & 7)) << 4));
      }
#pragma unroll
      for (int fj = 0; fj < 2; ++fj) {
        int col = wc * 64 + fj * 32 + l31;
        b[fj] = *(half8*)(bb + col * 128 + ((u ^ (col & 7)) << 4));
      }
#pragma unroll
      for (int fi = 0; fi < 2; ++fi)
#pragma unroll
        for (int fj = 0; fj < 2; ++fj)
          acc[fi][fj] = __builtin_amdgcn_mfma_f32_32x32x16_f16(
              a[fi], b[fj], acc[fi][fj], 0, 0, 0);
    }
  };

  // prologue (single full drain)
  Pf sA, sB;
  LOAD(0, sA);
  STORE(0, sA);
  LOAD(1, sB);
  __syncthreads();

  // main loop: 2 phases/iter, branchless clamped prefetch
  for (int t = 0; t < nt; t += 2) {
    int tA = (t + 2 < nt) ? t + 2 : nt - 1;
    LOAD(tA, sA);
    COMPUTE(0);
    STORE(1, sB);                 // tile t+1 (loaded 1.5 phases ago)
    BAR();

    int tB = (t + 3 < nt) ? t + 3 : nt - 1;
    LOAD(tB, sB);
    COMPUTE(1);
    STORE(0, sA);                 // tile t+2 (or harmless garbage at tail)
    BAR();
  }

  // epilogue: C/D layout (32x32): col=lane&31, row=(r&3)+8*(r>>2)+4*(lane>>5)
  if (use_ws) {
    float* o = target + (size_t)z * (size_t)BM * N;
#pragma unroll
    for (int fi = 0; fi < 2; ++fi)
#pragma unroll
      for (int fj = 0; fj < 2; ++fj) {
        int gc = n0 + wc * 64 + fj * 32 + l31;
#pragma unroll
        for (int r = 0; r < 16; ++r) {
          int gm = wr * 64 + fi * 32 + (r & 3) + 8 * (r >> 2) + 4 * l5;
          o[(size_t)gm * N + gc] = acc[fi][fj][r];
        }
      }
  } else {
#pragma unroll
    for (int fi = 0; fi < 2; ++fi)
#pragma unroll
      for (int fj = 0; fj < 2; ++fj) {
        int gc = n0 + wc * 64 + fj * 32 + l31;
#pragma unroll
        for (int r = 0; r < 16; ++r) {
          int gm = wr * 64 + fi * 32 + (r & 3) + 8 * (r >> 2) + 4 * l5;
          unsafeAtomicAdd(&target[(size_t)gm * N + gc], acc[fi][fj][r]);
        }
      }
  }
}

extern "C" void kernel_launch(void* const* d_in, const int* in_sizes, int n_in,
                              void* d_out, int out_size, void* d_ws, size_t ws_size,
                              hipStream_t stream) {
  const float* x = (const float*)d_in[0];
  const int* qw = (const int*)d_in[1];
  const int* qz = (const int*)d_in[2];
  const float* sc = (const float*)d_in[3];
  const float* bias = (const float*)d_in[4];
  float* out = (float*)d_out;

  int N = in_sizes[4];
  int K = (in_sizes[1] / N) * 8;
  int M = in_sizes[0] / K;           // == BM == 128
  int MN = M * N;
  size_t slice = (size_t)MN * 4;

  int S = 0;
  if (ws_size >= 8 * slice) S = 8;
  else if (ws_size >= 4 * slice) S = 4;
  else if (ws_size >= 2 * slice) S = 2;

  if (S > 0) {
    dim3 grid(N / BN, 1, S);
    qgemm_kernel<<<grid, 512, 0, stream>>>(x, qw, qz, sc, (float*)d_ws,
                                           N, K, S, 1);
    reduce_kernel<<<(MN / 4 + 255) / 256, 256, 0, stream>>>(
        (const float*)d_ws, bias, out, MN, N, S);
  } else {
    init_out_kernel<<<(MN / 4 + 255) / 256, 256, 0, stream>>>(bias, out, MN, N);
    dim3 grid(N / BN, 1, 8);
    qgemm_kernel<<<grid, 512, 0, stream>>>(x, qw, qz, sc, out, N, K, 8, 0);
  }
}